// Round 7
// baseline (410.463 us; speedup 1.0000x reference)
//
#include <hip/hip_runtime.h>
#include <stdint.h>

#define BATCH 4096
#define NEXP 64

typedef __bf16 bf16x8 __attribute__((ext_vector_type(8)));
typedef float f32x4 __attribute__((ext_vector_type(4)));
typedef float f32x8 __attribute__((ext_vector_type(8)));
typedef unsigned int u32x4 __attribute__((ext_vector_type(4)));
typedef unsigned short u16x4 __attribute__((ext_vector_type(4)));
typedef unsigned short u16x8 __attribute__((ext_vector_type(8)));

__device__ __forceinline__ unsigned short f2bf(float f) {
  unsigned u = __builtin_bit_cast(unsigned, f);
  u += 0x7fffu + ((u >> 16) & 1u);
  return (unsigned short)(u >> 16);
}
__device__ __forceinline__ float bf2f(unsigned short h) {
  unsigned u = ((unsigned)h) << 16;
  return __builtin_bit_cast(float, u);
}

// async global->LDS, 16B per lane (used only by the MNet GEMM).
__device__ __forceinline__ void async_copy16(const void* g, void* l) {
  __builtin_amdgcn_global_load_lds(
      (const __attribute__((address_space(1))) void*)(uintptr_t)g,
      (__attribute__((address_space(3))) void*)(uintptr_t)l, 16, 0, 0);
}

enum { AM_PLAIN = 0, AM_BN = 1 };

// ---------------------------------------------------------------------------
// MNet GEMM (round-4 structure, AM_PLAIN/AM_BN only).
// ---------------------------------------------------------------------------
template <int BM_, int BN_, int WR, int WC, int AMODE>
__global__ __launch_bounds__(256, 4) void gemm_k(
    const float* __restrict__ Af32, const float* __restrict__ scv,
    const float* __restrict__ shv, const float* __restrict__ alphaPtr,
    const unsigned short* __restrict__ PB, int K, int nsubsTot,
    float* __restrict__ Cp, const float* __restrict__ biasv, int N,
    int ktilesTot) {
  constexpr int MS = BM_ / 16;
  constexpr int NS = BN_ / 16;
  constexpr int WTM = BM_ / WR, WTN = BN_ / WC;
  constexpr int TM = WTM / 16, TN = WTN / 16;
  constexpr int PCH = MS / 2;

  __shared__ __align__(16) unsigned short As[2 * MS * 512];
  __shared__ __align__(16) unsigned short Bs[2 * NS * 512];

  const int tid = threadIdx.x;
  const int lane = tid & 63;
  const int wid = tid >> 6;
  const int wrow = wid / WC, wcol = wid % WC;

  const int m0 = blockIdx.x * BM_;
  const int ntile = blockIdx.y;
  const int n0 = ntile * BN_;

  float alpha = 0.f;
  if constexpr (AMODE == AM_BN) alpha = alphaPtr[0];

  f32x4 acc[TM][TN] = {};

  for (int kt = 0; kt < ktilesTot; ++kt) {
    const int k0 = kt * 64;

    for (int f = wid; f < 2 * NS; f += 4) {
      const int fkt = f / NS, fns = f % NS;
      const long fragIdx = (long)(k0 / 32 + fkt) * nsubsTot + (ntile * NS + fns);
      async_copy16(PB + fragIdx * 512 + lane * 8, &Bs[f * 512 + lane * 8]);
    }

#pragma unroll
    for (int p = 0; p < PCH; ++p) {
      const int id = p * 256 + tid;
      const int fA = id >> 6;
      const int q = id & 63;
      const int ksh = fA / MS, msub = fA % MS;
      const int kq = q >> 4, mrow = q & 15;
      const int m = msub * 16 + mrow;
      const int kg = k0 + ksh * 32 + kq * 8;
      const long mg = m0 + m;
      f32x8 vf;
      if constexpr (AMODE == AM_PLAIN) {
        const f32x4* src = (const f32x4*)(Af32 + mg * K + kg);
        f32x4 a0 = src[0], a1 = src[1];
#pragma unroll
        for (int j = 0; j < 4; ++j) { vf[j] = a0[j]; vf[4 + j] = a1[j]; }
      } else {
        const f32x4* src = (const f32x4*)(Af32 + mg * K + kg);
        f32x4 a0 = src[0], a1 = src[1];
        f32x4 s0 = *(const f32x4*)(scv + kg), s1 = *(const f32x4*)(scv + kg + 4);
        f32x4 h0 = *(const f32x4*)(shv + kg), h1 = *(const f32x4*)(shv + kg + 4);
#pragma unroll
        for (int j = 0; j < 4; ++j) {
          float v = fmaf(a0[j], s0[j], h0[j]);
          vf[j] = v >= 0.f ? v : alpha * v;
          float v2 = fmaf(a1[j], s1[j], h1[j]);
          vf[4 + j] = v2 >= 0.f ? v2 : alpha * v2;
        }
      }
      bf16x8 ob = __builtin_convertvector(vf, bf16x8);
      *(u16x8*)&As[id * 8] = __builtin_bit_cast(u16x8, ob);
    }
    __syncthreads();

#pragma unroll
    for (int ks = 0; ks < 2; ++ks) {
      bf16x8 af[TM], bfr[TN];
#pragma unroll
      for (int i = 0; i < TM; ++i) {
        const int msub = wrow * TM + i;
        af[i] = __builtin_bit_cast(
            bf16x8, *(const u32x4*)&As[(ks * MS + msub) * 512 + lane * 8]);
      }
#pragma unroll
      for (int j = 0; j < TN; ++j) {
        const int nsub = wcol * TN + j;
        bfr[j] = __builtin_bit_cast(
            bf16x8, *(const u32x4*)&Bs[(ks * NS + nsub) * 512 + lane * 8]);
      }
#pragma unroll
      for (int i = 0; i < TM; ++i)
#pragma unroll
        for (int j = 0; j < TN; ++j)
          acc[i][j] = __builtin_amdgcn_mfma_f32_16x16x32_bf16(af[i], bfr[j],
                                                              acc[i][j], 0, 0, 0);
    }
    __syncthreads();
  }

  const int q = lane >> 4, nn = lane & 15;
#pragma unroll
  for (int i = 0; i < TM; ++i) {
    const int rowb = m0 + wrow * WTM + i * 16 + q * 4;
#pragma unroll
    for (int j = 0; j < TN; ++j) {
      const int col = n0 + wcol * WTN + j * 16 + nn;
      const float bv = biasv ? biasv[col] : 0.f;
#pragma unroll
      for (int r = 0; r < 4; ++r)
        Cp[(long)(rowb + r) * N + col] = acc[i][j][r] + bv;
    }
  }
}

// ---------------------------------------------------------------------------
// Expert GEMM (round-7): barrier-free, LDS-free, XCD-local, ring-4 prefetch.
//   C_slice[b,n] = sum_{e in slice} wn[b,e]*(z@W_e^T + b_e)
//   Grid is FLAT 1D: bx = mb*NC + combo; combo (= ntile+NTILE*slice) occupies
//   the LOW bits so round-robin dispatch pins each combo to one XCD
//   (XCD = bx % 8). With EPB=8 slices, per-XCD working set = B(~1MB) +
//   zpk(2MB) < 4MB L2 -> B loads become L2-local (~200cy).
//   B fragment index is LINEAR in t = ei*KT2+kt -> 4-slot register ring
//   (slot = kt&3, compile-time) issues each load 4 kt before use.
//   Waves 1x4 own disjoint column strips (no duplicated B traffic).
// ---------------------------------------------------------------------------
template <int BN_, int KE_, int EPB, int NTILE>
__global__ __launch_bounds__(256, 2) void egemm_k(
    const unsigned short* __restrict__ zpk, const float* __restrict__ wnT,
    const float* __restrict__ bias, const unsigned short* __restrict__ PB,
    float* __restrict__ Cbase, long partStride, int N, int nsubsTot) {
  constexpr int KT2 = KE_ / 32;  // K-subtiles per expert
  constexpr int NS = BN_ / 16;
  constexpr int TN = NS / 4;  // 4 waves split columns disjointly
  constexpr int TM = 4;       // BM=64: each wave covers all rows
  constexpr int NC = NTILE * (NEXP / EPB);
  constexpr int T = EPB * KT2;
  constexpr int U = ((KT2 & 3) == 0) ? 1 : (4 / KT2);  // keep slot compile-time

  const int tid = threadIdx.x, lane = tid & 63, wid = tid >> 6;
  const int bx = blockIdx.x;
  const int combo = bx % NC;  // low bits -> XCD-local
  const int mb = bx / NC;
  const int ntile = combo % NTILE;
  const int slice = combo / NTILE;
  const int e0 = slice * EPB;
  const int n0 = ntile * BN_;
  float* __restrict__ Cp = Cbase + (long)slice * partStride;
  const int nn = lane & 15, q = lane >> 4;

  // A fragments (expert-invariant). Compiler may keep resident or remat from
  // L1/L2 (zpk tile is 32KB, XCD-local after swizzle).
  const unsigned short* Aw = zpk + (long)mb * (KT2 * 4 * 512);
  u32x4 areg[TM][KT2];
#pragma unroll
  for (int i = 0; i < TM; ++i)
#pragma unroll
    for (int kt = 0; kt < KT2; ++kt)
      areg[i][kt] = *(const u32x4*)(Aw + (kt * 4 + i) * 512 + lane * 8);

  // B stream base: fragment t, col j at Bt + t*kstr + j*512.
  const long kstr = (long)nsubsTot * 512;
  const unsigned short* Bt = PB + (long)e0 * KT2 * kstr +
                             ((long)ntile * NS + wid * TN) * 512 + lane * 8;

  u32x4 ring[4][TN];
#pragma unroll
  for (int t = 0; t < 4; ++t)
#pragma unroll
    for (int j = 0; j < TN; ++j)
      ring[t][j] = *(const u32x4*)(Bt + (long)t * kstr + j * 512);

  f32x4 mainAcc[TM][TN] = {};

  for (int eb = 0; eb < EPB; eb += U) {
#pragma unroll
    for (int u = 0; u < U; ++u) {
      const int ei = eb + u;
      const int e = e0 + ei;
      f32x4 tmp[TM][TN];
#pragma unroll
      for (int j = 0; j < TN; ++j) {
        const float bv = bias[(long)e * N + n0 + wid * (TN * 16) + j * 16 + nn];
        f32x4 t4 = {bv, bv, bv, bv};
#pragma unroll
        for (int i = 0; i < TM; ++i) tmp[i][j] = t4;
      }
#pragma unroll
      for (int kt = 0; kt < KT2; ++kt) {
        const int slot = (u * KT2 + kt) & 3;
#pragma unroll
        for (int i = 0; i < TM; ++i) {
          bf16x8 af = __builtin_bit_cast(bf16x8, areg[i][kt]);
#pragma unroll
          for (int j = 0; j < TN; ++j)
            tmp[i][j] = __builtin_amdgcn_mfma_f32_16x16x32_bf16(
                af, __builtin_bit_cast(bf16x8, ring[slot][j]), tmp[i][j], 0, 0,
                0);
        }
        {
          const int t = ei * KT2 + kt;
          const int tl = (t + 4 < T) ? (t + 4) : (T - 1);  // clamp: harmless
#pragma unroll
          for (int j = 0; j < TN; ++j)
            ring[slot][j] = *(const u32x4*)(Bt + (long)tl * kstr + j * 512);
        }
      }
      // mainAcc += wn[:,e] (fp32, per-row) * tmp
#pragma unroll
      for (int i = 0; i < TM; ++i) {
        const int rowb = mb * 64 + i * 16 + q * 4;
        f32x4 wn4 = *(const f32x4*)(wnT + (long)e * BATCH + rowb);
#pragma unroll
        for (int j = 0; j < TN; ++j) mainAcc[i][j] += wn4 * tmp[i][j];
      }
    }
  }

#pragma unroll
  for (int i = 0; i < TM; ++i) {
    const int rowb = mb * 64 + i * 16 + q * 4;
#pragma unroll
    for (int j = 0; j < TN; ++j) {
      const int col = n0 + wid * (TN * 16) + j * 16 + nn;
#pragma unroll
      for (int r = 0; r < 4; ++r)
        Cp[(long)(rowb + r) * N + col] = mainAcc[i][j][r];
    }
  }
}

// H[idx] = sum over nparts partials, written in place over partial 0.
__global__ void hbuild_k(float* __restrict__ P, long partStride, int nparts,
                         int total4) {
  const int idx = blockIdx.x * 256 + threadIdx.x;
  if (idx >= total4) return;
  f32x4 s = *(const f32x4*)(P + (long)idx * 4);
  for (int p = 1; p < nparts; ++p)
    s += *(const f32x4*)(P + p * partStride + (long)idx * 4);
  *(f32x4*)(P + (long)idx * 4) = s;
}

// BN stats: 4 columns per block, float4 row reads.
__global__ void stats_k(const float* __restrict__ H, int C,
                        const float* __restrict__ g, const float* __restrict__ b,
                        float* __restrict__ scv, float* __restrict__ shv) {
  const int c0 = blockIdx.x * 4;
  f32x4 s = {0.f, 0.f, 0.f, 0.f}, s2 = {0.f, 0.f, 0.f, 0.f};
  for (int r = threadIdx.x; r < BATCH; r += 256) {
    f32x4 x = *(const f32x4*)(H + (long)r * C + c0);
    s += x;
    s2 += x * x;
  }
  __shared__ f32x4 sb[256], qb[256];
  sb[threadIdx.x] = s;
  qb[threadIdx.x] = s2;
  __syncthreads();
  for (int st = 128; st > 0; st >>= 1) {
    if (threadIdx.x < st) {
      sb[threadIdx.x] += sb[threadIdx.x + st];
      qb[threadIdx.x] += qb[threadIdx.x + st];
    }
    __syncthreads();
  }
  if (threadIdx.x < 4) {
    const int c = c0 + threadIdx.x;
    float mu = sb[0][threadIdx.x] * (1.f / BATCH);
    float var = qb[0][threadIdx.x] * (1.f / BATCH) - mu * mu;
    float isig = 1.f / sqrtf(var + 1e-5f);
    float sc_ = g[c] * isig;
    scv[c] = sc_;
    shv[c] = b[c] - mu * sc_;
  }
}

// zpk = packed-A-fragment bf16 of prelu(bn(H)); C=256 fixed.
__global__ void zbuild_pk(const float* __restrict__ H,
                          const float* __restrict__ scv,
                          const float* __restrict__ shv,
                          const float* __restrict__ alphaPtr,
                          unsigned short* __restrict__ zpk) {
  const int c = blockIdx.x * 256 + threadIdx.x;  // 131072 total
  const float alpha = alphaPtr[0];
  const int mb = c >> 11, r = c & 2047;
  const int kt = r >> 8, q2 = r & 255;
  const int msub = q2 >> 6, ln = q2 & 63;
  const int row = mb * 64 + msub * 16 + (ln & 15);
  const int col = kt * 32 + (ln >> 4) * 8;
  const float* src = H + (long)row * 256 + col;
  f32x4 a0 = *(const f32x4*)src, a1 = *(const f32x4*)(src + 4);
  f32x4 s0 = *(const f32x4*)(scv + col), s1 = *(const f32x4*)(scv + col + 4);
  f32x4 h0 = *(const f32x4*)(shv + col), h1 = *(const f32x4*)(shv + col + 4);
  u16x8 o;
#pragma unroll
  for (int j = 0; j < 4; ++j) {
    float v = fmaf(a0[j], s0[j], h0[j]);
    v = v >= 0.f ? v : alpha * v;
    o[j] = f2bf(v);
    float v2 = fmaf(a1[j], s1[j], h1[j]);
    v2 = v2 >= 0.f ? v2 : alpha * v2;
    o[4 + j] = f2bf(v2);
  }
  *(u16x8*)(zpk + (long)c * 8) = o;
}

// x0 (fp32 [4096,64]) -> packed-A-fragment bf16 (K=64: 2 kt per mblock).
__global__ void cast_pk(const float* __restrict__ x,
                        unsigned short* __restrict__ zpk) {
  const int c = blockIdx.x * 256 + threadIdx.x;  // 32768 total
  const int mb = c >> 9, r = c & 511;
  const int kt = r >> 8, q2 = r & 255;
  const int msub = q2 >> 6, ln = q2 & 63;
  const int row = mb * 64 + msub * 16 + (ln & 15);
  const int col = kt * 32 + (ln >> 4) * 8;
  const float* src = x + (long)row * 64 + col;
  f32x4 a0 = *(const f32x4*)src, a1 = *(const f32x4*)(src + 4);
  u16x8 o;
#pragma unroll
  for (int j = 0; j < 4; ++j) {
    o[j] = f2bf(a0[j]);
    o[4 + j] = f2bf(a1[j]);
  }
  *(u16x8*)(zpk + (long)c * 8) = o;
}

// w = prelu(bn(G3)) fp32, + global sum (for wn = w/w_sum)
__global__ void wbuild_k(const float* __restrict__ G, const float* __restrict__ scv,
                         const float* __restrict__ shv,
                         const float* __restrict__ alphaPtr,
                         float* __restrict__ w, float* __restrict__ wsum) {
  const int idx = blockIdx.x * 256 + threadIdx.x;  // exactly 65536 threads
  const float alpha = alphaPtr[0];
  const int c0 = (idx * 4) & 63;
  f32x4 x = *(const f32x4*)(G + (long)idx * 4);
  f32x4 sv = *(const f32x4*)(scv + c0);
  f32x4 hv = *(const f32x4*)(shv + c0);
  f32x4 o;
  float part = 0.f;
#pragma unroll
  for (int j = 0; j < 4; ++j) {
    float v = fmaf(x[j], sv[j], hv[j]);
    v = v >= 0.f ? v : alpha * v;
    o[j] = v;
    part += v;
  }
  *(f32x4*)(w + (long)idx * 4) = o;
  __shared__ float sb[256];
  sb[threadIdx.x] = part;
  __syncthreads();
  for (int st = 128; st > 0; st >>= 1) {
    if (threadIdx.x < st) sb[threadIdx.x] += sb[threadIdx.x + st];
    __syncthreads();
  }
  if (threadIdx.x == 0) atomicAdd(wsum, sb[0]);
}

__global__ void inv_k(const float* __restrict__ wsum, float* __restrict__ invp) {
  if (threadIdx.x == 0 && blockIdx.x == 0) invp[0] = 1.0f / wsum[0];
}

// wnT[e][b] = w[b][e] / w_sum  (fp32 transposed table for egemm row-scaling)
__global__ void wntbuild_k(const float* __restrict__ w,
                           const float* __restrict__ invp,
                           float* __restrict__ wnT) {
  const int idx = blockIdx.x * 256 + threadIdx.x;  // 262144
  const int e = idx >> 12, b = idx & 4095;
  wnT[idx] = w[(long)b * NEXP + e] * invp[0];
}

// W[e,o,i] fp32 (+optional bias rows) -> fragment-major bf16
__global__ void prepack_k(const float* __restrict__ W, const float* __restrict__ bias,
                          unsigned short* __restrict__ PB, int O, int shI, int EI,
                          long totalChunks) {
  const long t = (long)blockIdx.x * 256 + threadIdx.x;
  if (t >= totalChunks) return;
  const int lane = (int)(t & 63);
  const long frag = t >> 6;
  const int nsubs = O / 16;
  const int nsub = (int)(frag % nsubs);
  const long ktile = frag / nsubs;
  const int n = nsub * 16 + (lane & 15);
  const int k = (int)(ktile * 32 + (lane >> 4) * 8);
  u16x8 o;
  if (k < EI) {
    const int e = k >> shI;
    const int i0 = k & ((1 << shI) - 1);
    const float* src = W + ((long)e * O + n) * (1 << shI) + i0;
    f32x4 a0 = *(const f32x4*)src;
    f32x4 a1 = *(const f32x4*)(src + 4);
#pragma unroll
    for (int j = 0; j < 4; ++j) {
      o[j] = f2bf(a0[j]);
      o[4 + j] = f2bf(a1[j]);
    }
  } else {
#pragma unroll
    for (int j = 0; j < 8; ++j) {
      const int ee = k + j - EI;
      o[j] = f2bf(bias[(long)ee * O + n]);
    }
  }
  *(u16x8*)(PB + t * 8) = o;
}

__global__ void reduceN_k(const float* __restrict__ P, long partStride, int nparts,
                          float* __restrict__ out, int total4) {
  const int idx = blockIdx.x * 256 + threadIdx.x;
  if (idx >= total4) return;
  f32x4 s = {0.f, 0.f, 0.f, 0.f};
  for (int p = 0; p < nparts; ++p) s += *(const f32x4*)(P + p * partStride + (long)idx * 4);
  *(f32x4*)(out + (long)idx * 4) = s;
}

// ---------------------------------------------------------------------------
extern "C" void kernel_launch(void* const* d_in, const int* in_sizes, int n_in,
                              void* d_out, int out_size, void* d_ws, size_t ws_size,
                              hipStream_t stream) {
  const float* m0 = (const float*)d_in[0];
  const float* x0 = (const float*)d_in[1];
  const float* mW1 = (const float*)d_in[2];
  const float* mb1 = (const float*)d_in[3];
  const float* mg1 = (const float*)d_in[4];
  const float* mbe1 = (const float*)d_in[5];
  const float* ma1 = (const float*)d_in[6];
  const float* mW2 = (const float*)d_in[7];
  const float* mb2 = (const float*)d_in[8];
  const float* mg2 = (const float*)d_in[9];
  const float* mbe2 = (const float*)d_in[10];
  const float* ma2 = (const float*)d_in[11];
  const float* mW3 = (const float*)d_in[12];
  const float* mb3 = (const float*)d_in[13];
  const float* mg3 = (const float*)d_in[14];
  const float* mbe3 = (const float*)d_in[15];
  const float* ma3 = (const float*)d_in[16];
  const float* Wenc0 = (const float*)d_in[17];
  const float* benc0 = (const float*)d_in[18];
  const float* Wenc1 = (const float*)d_in[19];
  const float* benc1 = (const float*)d_in[20];
  const float* Wdec0 = (const float*)d_in[21];
  const float* bdec0 = (const float*)d_in[22];
  const float* Wdec1 = (const float*)d_in[23];
  const float* bdec1 = (const float*)d_in[24];
  const float* bng = (const float*)d_in[25];
  const float* bnb = (const float*)d_in[26];
  const float* aexp = (const float*)d_in[27];

  // 8 expert-slices x 2 ntile -> 16 combos -> 2 combos/XCD, grid 1024
  // (= 2 blocks/CU x 2 rounds exactly). dec1: 16 slices x 1 ntile.
  const int SPL = 8, SPLD = 16;

  char* base = (char*)d_ws;
  size_t off = 0;
  auto alloc = [&](size_t bytes) {
    void* p = base + off;
    off = (off + bytes + 255) & ~(size_t)255;
    return p;
  };
  unsigned short* PB = (unsigned short*)alloc(16448L * 256 * 2);  // 8.4 MB
  float* Pb = (float*)alloc((size_t)SPL * BATCH * 256 * 4);       // 32 MB partials
  float* P0 = Pb;                      // MNet H1 [4096,256] / H3 [4096,64]
  float* P1 = Pb + (long)BATCH * 256;  // MNet H2 [4096,128]
  unsigned short* zApk = (unsigned short*)alloc(BATCH * 256 * 2);
  unsigned short* zBpk = (unsigned short*)alloc(BATCH * 256 * 2);
  unsigned short* x0pk = (unsigned short*)alloc(BATCH * 64 * 2);
  float* wbuf = (float*)alloc(BATCH * 64 * 4);
  float* wnT = (float*)alloc((size_t)NEXP * BATCH * 4);  // 1 MB
  float* scv = (float*)alloc(256 * 4);
  float* shv = (float*)alloc(256 * 4);
  float* wsum = (float*)alloc(256);
  float* invp = (float*)alloc(256);

  const dim3 blk(256);
  const long PS = BATCH * 256;  // partial stride (elements)

  // ---- MNet L1: H1 = m0 @ mW1^T + mb1 -> P0 [4096,256]
  prepack_k<<<16, blk, 0, stream>>>(mW1, nullptr, PB, 256, 7, 128, 4096);
  gemm_k<64, 128, 2, 2, AM_PLAIN><<<dim3(64, 2, 1), blk, 0, stream>>>(
      m0, nullptr, nullptr, nullptr, PB, 128, 16, P0, mb1, 256, 2);
  stats_k<<<64, blk, 0, stream>>>(P0, 256, mg1, mbe1, scv, shv);

  // ---- MNet L2: H2 = prelu(bn(H1)) @ mW2^T + mb2 -> P1 [4096,128]
  prepack_k<<<16, blk, 0, stream>>>(mW2, nullptr, PB, 128, 8, 256, 4096);
  gemm_k<64, 128, 2, 2, AM_BN><<<dim3(64, 1, 1), blk, 0, stream>>>(
      P0, scv, shv, ma1, PB, 256, 8, P1, mb2, 128, 4);
  stats_k<<<32, blk, 0, stream>>>(P1, 128, mg2, mbe2, scv, shv);

  // ---- MNet L3: H3 = prelu(bn(H2)) @ mW3^T + mb3 -> P0 [4096,64]
  prepack_k<<<4, blk, 0, stream>>>(mW3, nullptr, PB, 64, 7, 128, 1024);
  gemm_k<64, 64, 2, 2, AM_BN><<<dim3(64, 1, 1), blk, 0, stream>>>(
      P1, scv, shv, ma2, PB, 128, 4, P0, mb3, 64, 2);
  stats_k<<<16, blk, 0, stream>>>(P0, 64, mg3, mbe3, scv, shv);

  // ---- w = prelu(bn(H3)); w_sum; wnT = (w/w_sum)^T; x0 -> packed bf16
  hipMemsetAsync(wsum, 0, 4, stream);
  wbuild_k<<<256, blk, 0, stream>>>(P0, scv, shv, ma3, wbuf, wsum);
  inv_k<<<1, 64, 0, stream>>>(wsum, invp);
  wntbuild_k<<<1024, blk, 0, stream>>>(wbuf, invp, wnT);
  cast_pk<<<128, blk, 0, stream>>>(x0, x0pk);

  // ---- enc0: KE=64
  prepack_k<<<512, blk, 0, stream>>>(Wenc0, nullptr, PB, 256, 6, 4096, 131072);
  egemm_k<128, 64, 8, 2><<<dim3(1024), blk, 0, stream>>>(
      x0pk, wnT, benc0, PB, Pb, PS, 256, 16);
  hbuild_k<<<1024, blk, 0, stream>>>(Pb, PS, SPL, 262144);
  stats_k<<<64, blk, 0, stream>>>(Pb, 256, bng, bnb, scv, shv);
  zbuild_pk<<<512, blk, 0, stream>>>(Pb, scv, shv, aexp, zApk);

  // ---- enc1: KE=256
  prepack_k<<<2048, blk, 0, stream>>>(Wenc1, nullptr, PB, 256, 8, 16384, 524288);
  egemm_k<128, 256, 8, 2><<<dim3(1024), blk, 0, stream>>>(
      zApk, wnT, benc1, PB, Pb, PS, 256, 16);
  hbuild_k<<<1024, blk, 0, stream>>>(Pb, PS, SPL, 262144);
  stats_k<<<64, blk, 0, stream>>>(Pb, 256, bng, bnb, scv, shv);
  zbuild_pk<<<512, blk, 0, stream>>>(Pb, scv, shv, aexp, zBpk);

  // ---- dec0
  prepack_k<<<2048, blk, 0, stream>>>(Wdec0, nullptr, PB, 256, 8, 16384, 524288);
  egemm_k<128, 256, 8, 2><<<dim3(1024), blk, 0, stream>>>(
      zBpk, wnT, bdec0, PB, Pb, PS, 256, 16);
  hbuild_k<<<1024, blk, 0, stream>>>(Pb, PS, SPL, 262144);
  stats_k<<<64, blk, 0, stream>>>(Pb, 256, bng, bnb, scv, shv);
  zbuild_pk<<<512, blk, 0, stream>>>(Pb, scv, shv, aexp, zApk);

  // ---- dec1: N=64, 16 expert-slices of 4 -> partials [4096,64]
  prepack_k<<<512, blk, 0, stream>>>(Wdec1, nullptr, PB, 64, 8, 16384, 131072);
  egemm_k<64, 256, 4, 1><<<dim3(1024), blk, 0, stream>>>(
      zApk, wnT, bdec1, PB, Pb, (long)BATCH * 64, 64, 4);
  reduceN_k<<<256, blk, 0, stream>>>(Pb, (long)BATCH * 64, SPLD, (float*)d_out,
                                     65536);

  (void)in_sizes; (void)n_in; (void)out_size; (void)ws_size;
}